// Round 18
// baseline (50.041 us; speedup 1.0000x reference)
//
#include <hip/hip_runtime.h>
#include <math.h>

// HPSS fused — r17 structure with fp16 tile CONTAINER (f32 math) + (256,6).
// S (2,1,1025,2048) fp32. harm = median_31 along T (zero pad), perc = along F.
// outH = S*h^2/(h^2+p^2), outP = S*p^2/(h^2+p^2)   (softmask Z cancels).
//
// r17 datum: pruning 30 VALU/sort moved dur by 0.0 -> NOT issue-bound; the
// ~53% stall fraction is the target. r7's occupancy-null was measured on the
// LDS-fed fp16-math kernel (different stall anatomy: serial per-slide
// ds_reads). This round tests occupancy on the WINNING reg-fed structure:
//  - tile stored as fp16 (container only; feed reads cvt to f32, +76 ops
//    ~ +7%; median commutes with monotone cast — numerics proven r7-r12)
//    -> LDS 12.2 + 4.2 = 16.4KB.
//  - __launch_bounds__(256,6): 85-VGPR cap (> r16's measured 64, no spill)
//    -> 6 blocks/CU (was 4), +50% waves/SIMD.
// Everything else = r17: RW=8 reg-fed f32 slides, pruned Batcher, float4
// staging, T14 2-tile prefetch, barriered H->P, grid 16x33x2 = 1056.

#define DIM_T 2048
#define DIM_F 1025
#define HALF 15
#define FT 32            // output f-rows per tile
#define TT 64            // output t-cols per tile
#define RW 8             // outputs per thread along sliding axis
#define TROWS (FT + 30)  // 62 staged rows
#define VPR 24           // float4 vecs per row (96 cols, [t0-16, t0+80))
#define TSTRH 98         // tile stride in halves; 49 dwords (odd) -> conflict-free
#define HSTRH 66         // hl stride in halves (33 dwords, odd)
#define NVEC (TROWS * VPR)   // 1488
#define FEED (RW + 30)   // 38

typedef _Float16 h16;

__device__ __forceinline__ void ce(float& a, float& b) {
    const float mn = fminf(a, b);
    b = fmaxf(a, b);
    a = mn;
}

// Batcher-32 with all CEs touching index 31 pruned (a[31] = +INF is inert).
__device__ __forceinline__ void sort32(float (&a)[32]) {
#pragma unroll
    for (int p = 1; p < 32; p <<= 1) {
#pragma unroll
        for (int k = p; k >= 1; k >>= 1) {
#pragma unroll
            for (int j = k & (p - 1); j + k < 32; j += 2 * k) {
#pragma unroll
                for (int i = 0; i < k; ++i) {
                    if (i + j + k < 31) {   // ==31 CEs are no-ops on +INF
                        if ((i + j) / (2 * p) == (i + j + k) / (2 * p)) {
                            ce(a[i + j], a[i + j + k]);
                        }
                    }
                }
            }
        }
    }
}

// sorted-window slide: remove x_old (present in w[0..30]), insert x_new.
// w[31] must be +INF and is preserved. 31 indep (cmp+sel) + 31 indep med3.
__device__ __forceinline__ void slide(float (&w)[32], float x_old, float x_new) {
    float dprev = (w[0] < x_old) ? w[0] : w[1];
    float rprev = fminf(x_new, dprev);
#pragma unroll
    for (int i = 1; i < 31; ++i) {
        const float di = (w[i] < x_old) ? w[i] : w[i + 1];
        const float ri = __builtin_amdgcn_fmed3f(dprev, x_new, di);
        w[i - 1] = rprev;
        dprev = di;
        rprev = ri;
    }
    w[30] = rprev;
}

// load one staging vector for tile at t0x (vec index li = it*256+tid)
__device__ __forceinline__ float4 load_vec(const float* __restrict__ Sb,
                                           int f0, int t0x, int li) {
    float4 v = make_float4(0.f, 0.f, 0.f, 0.f);
    if (li < NVEC) {
        const int row = li / VPR;
        const int pos = li - row * VPR;
        const int f  = f0 - HALF + row;
        const int tg = t0x - 16 + pos * 4;
        if ((unsigned)f < (unsigned)DIM_F && (unsigned)tg <= (unsigned)(DIM_T - 4))
            v = *(const float4*)&Sb[(size_t)f * DIM_T + tg];
    }
    return v;
}

// write staged vec as fp16 (two packed dword stores after conversion)
__device__ __forceinline__ void write_vec(h16* __restrict__ tile, int li, float4 v) {
    if (li < NVEC) {
        const int row = li / VPR;
        const int pos = li - row * VPR;
        h16* p = &tile[row * TSTRH + pos * 4];
        p[0] = (h16)v.x; p[1] = (h16)v.y; p[2] = (h16)v.z; p[3] = (h16)v.w;
    }
}

// One 32x64 tile: H phase, barrier, P phase (r13's proven structure).
__device__ __forceinline__ void compute_tile(const h16* __restrict__ tile,
                                             h16* __restrict__ hl,
                                             float* __restrict__ outH,
                                             float* __restrict__ outP,
                                             int tid, int f0, int b, int t0x) {
    // ---- phase H: harmonic medians (slide along t) -> hl[f][t] ----
    {
        const int fl = tid & 31;          // output f row 0..31
        const int tb = (tid >> 5) * RW;   // t chunk base 0..56
        const h16* lr = tile + (fl + HALF) * TSTRH + tb + 1;

        float r[FEED];
#pragma unroll
        for (int d = 0; d < FEED; ++d) r[d] = (float)lr[d];

        float w[32];
        w[31] = INFINITY;
#pragma unroll
        for (int d = 0; d < 31; ++d) w[d] = r[d];
        sort32(w);
#pragma unroll
        for (int s = 0; s < RW; ++s) {
            hl[fl * HSTRH + tb + s] = (h16)w[15];
            if (s < RW - 1) slide(w, r[s], r[s + 31]);
        }
    }
    __syncthreads();
    // ---- phase P: percussive medians (slide along f) + combine + store ----
    {
        const int lane = tid & 63;        // t within tile
        const int fb   = (tid >> 6) * RW; // f chunk base 0,8,16,24
        const int t    = t0x + lane;

        float r[FEED];
#pragma unroll
        for (int d = 0; d < FEED; ++d)
            r[d] = (float)tile[(fb + d) * TSTRH + 16 + lane];
        h16 hp[RW];
#pragma unroll
        for (int s = 0; s < RW; ++s) hp[s] = hl[(fb + s) * HSTRH + lane];

        float w[32];
        w[31] = INFINITY;
#pragma unroll
        for (int d = 0; d < 31; ++d) w[d] = r[d];
        sort32(w);
#pragma unroll
        for (int s = 0; s < RW; ++s) {
            const int f = f0 + fb + s;
            if (f < DIM_F) {
                const float perc = w[15];
                const float harm = (float)hp[s];
                const float sv   = r[s + 15];   // center element (fp16-rounded, r9-proven)
                const float h2 = harm * harm;
                const float p2 = perc * perc;
                const float inv = __builtin_amdgcn_rcpf(h2 + p2);  // 0 -> INF; (sv*0)*INF=NaN matches ref 0/0
                const size_t oi = ((size_t)b * DIM_F + f) * DIM_T + t;
                outH[oi] = sv * h2 * inv;
                outP[oi] = sv * p2 * inv;
            }
            if (s < RW - 1) slide(w, r[s], r[s + 31]);
        }
    }
}

__global__ __launch_bounds__(256, 6) void hpss_fused(const float* __restrict__ S,
                                                     float* __restrict__ outH,
                                                     float* __restrict__ outP) {
    __shared__ h16 tile[TROWS * TSTRH];  // 12152 B
    __shared__ h16 hl[FT * HSTRH];       //  4224 B

    const int tid = threadIdx.x;
    const int t0A = blockIdx.x * (2 * TT);      // tile A
    const int t0B = t0A + TT;                   // tile B
    const int f0  = blockIdx.y * FT;
    const int b   = blockIdx.z;
    const float* __restrict__ Sb = S + (size_t)b * DIM_F * DIM_T;

    // stage tile A directly
#pragma unroll
    for (int it = 0; it < 6; ++it)
        write_vec(tile, it * 256 + tid, load_vec(Sb, f0, t0A, it * 256 + tid));

    // issue tile B loads NOW; consumed a full compute-phase later (T14)
    float4 bv[6];
#pragma unroll
    for (int it = 0; it < 6; ++it) bv[it] = load_vec(Sb, f0, t0B, it * 256 + tid);

    __syncthreads();
    compute_tile(tile, hl, outH, outP, tid, f0, b, t0A);
    __syncthreads();                    // all waves done reading tile A

#pragma unroll
    for (int it = 0; it < 6; ++it) write_vec(tile, it * 256 + tid, bv[it]);
    __syncthreads();
    compute_tile(tile, hl, outH, outP, tid, f0, b, t0B);
}

extern "C" void kernel_launch(void* const* d_in, const int* in_sizes, int n_in,
                              void* d_out, int out_size, void* d_ws, size_t ws_size,
                              hipStream_t stream) {
    const float* S = (const float*)d_in[0];
    float* outH = (float*)d_out;
    float* outP = outH + (size_t)2 * DIM_F * DIM_T;

    dim3 grid(DIM_T / (2 * TT), (DIM_F + FT - 1) / FT, 2);  // 16 x 33 x 2 = 1056
    hpss_fused<<<grid, 256, 0, stream>>>(S, outH, outP);
}

// Round 19
// 41.340 us; speedup vs baseline: 1.2105x; 1.2105x over previous
//
#include <hip/hip_runtime.h>
#include <math.h>

// HPSS fused — r17 verbatim with ONE change: __launch_bounds__(256,5).
// S (2,1,1025,2048) fp32. harm = median_31 along T (zero pad), perc = along F.
// outH = S*h^2/(h^2+p^2), outP = S*p^2/(h^2+p^2)   (softmask Z cancels).
//
// r18 lesson (3rd confirmation): caps below this structure's ~90-100 VGPR
// demand trigger the allocator's spill-everything fallback (VGPR=40 +
// WRITE 105MB). Clean occupancy probe: (256,5) = 102-VGPR cap, which the
// structure plausibly FITS (r11 demand 44; + bv[6] ~24 -> ~75-95).
// VGPR file = 512 slots/lane/SIMD: <=102 -> 5 waves/SIMD (was 4 at 128-cap).
// LDS 28.7KB already allows 5 blocks/CU -> occupancy becomes VGPR-bound
// only, so this isolates the occupancy variable without touching structure.
// Tripwire: WRITE_SIZE >> 33MB = spill = invalid test, revert to r17.
// Core: RW=8 reg-fed f32 slides (delete+insert, O(1) dep depth), pruned
// Batcher-32, float4 staging, T14 2-tile prefetch, fp16 hl container,
// 32(f)x64(t) tiles x2/block, grid 16x33x2 = 1056.

#define DIM_T 2048
#define DIM_F 1025
#define HALF 15
#define FT 32            // output f-rows per tile
#define TT 64            // output t-cols per tile
#define RW 8             // outputs per thread along sliding axis
#define TROWS (FT + 30)  // 62 staged rows
#define VPR 24           // float4 vecs per row (96 cols, [t0-16, t0+80))
#define TSTR 97          // dwords; odd -> conflict-free for both phases
#define HSTRH 66         // hl stride in halves (33 dwords, odd)
#define NVEC (TROWS * VPR)   // 1488
#define FEED (RW + 30)   // 38

typedef _Float16 h16;

__device__ __forceinline__ void ce(float& a, float& b) {
    const float mn = fminf(a, b);
    b = fmaxf(a, b);
    a = mn;
}

// Batcher-32 with all CEs touching index 31 pruned (a[31] = +INF is inert).
__device__ __forceinline__ void sort32(float (&a)[32]) {
#pragma unroll
    for (int p = 1; p < 32; p <<= 1) {
#pragma unroll
        for (int k = p; k >= 1; k >>= 1) {
#pragma unroll
            for (int j = k & (p - 1); j + k < 32; j += 2 * k) {
#pragma unroll
                for (int i = 0; i < k; ++i) {
                    if (i + j + k < 31) {   // ==31 CEs are no-ops on +INF
                        if ((i + j) / (2 * p) == (i + j + k) / (2 * p)) {
                            ce(a[i + j], a[i + j + k]);
                        }
                    }
                }
            }
        }
    }
}

// sorted-window slide: remove x_old (present in w[0..30]), insert x_new.
// w[31] must be +INF and is preserved. 31 indep (cmp+sel) + 31 indep med3.
__device__ __forceinline__ void slide(float (&w)[32], float x_old, float x_new) {
    float dprev = (w[0] < x_old) ? w[0] : w[1];
    float rprev = fminf(x_new, dprev);
#pragma unroll
    for (int i = 1; i < 31; ++i) {
        const float di = (w[i] < x_old) ? w[i] : w[i + 1];
        const float ri = __builtin_amdgcn_fmed3f(dprev, x_new, di);
        w[i - 1] = rprev;
        dprev = di;
        rprev = ri;
    }
    w[30] = rprev;
}

// load one staging vector for tile at t0x (vec index li = it*256+tid)
__device__ __forceinline__ float4 load_vec(const float* __restrict__ Sb,
                                           int f0, int t0x, int li) {
    float4 v = make_float4(0.f, 0.f, 0.f, 0.f);
    if (li < NVEC) {
        const int row = li / VPR;
        const int pos = li - row * VPR;
        const int f  = f0 - HALF + row;
        const int tg = t0x - 16 + pos * 4;
        if ((unsigned)f < (unsigned)DIM_F && (unsigned)tg <= (unsigned)(DIM_T - 4))
            v = *(const float4*)&Sb[(size_t)f * DIM_T + tg];
    }
    return v;
}

__device__ __forceinline__ void write_vec(float* __restrict__ tile, int li, float4 v) {
    if (li < NVEC) {
        const int row = li / VPR;
        const int pos = li - row * VPR;
        float* p = &tile[row * TSTR + pos * 4];
        p[0] = v.x; p[1] = v.y; p[2] = v.z; p[3] = v.w;
    }
}

// One 32x64 tile: H phase, barrier, P phase (r13's proven structure).
__device__ __forceinline__ void compute_tile(const float* __restrict__ tile,
                                             h16* __restrict__ hl,
                                             float* __restrict__ outH,
                                             float* __restrict__ outP,
                                             int tid, int f0, int b, int t0x) {
    // ---- phase H: harmonic medians (slide along t) -> hl[f][t] ----
    {
        const int fl = tid & 31;          // output f row 0..31
        const int tb = (tid >> 5) * RW;   // t chunk base 0..56
        const float* lr = tile + (fl + HALF) * TSTR + tb + 1;

        float r[FEED];
#pragma unroll
        for (int d = 0; d < FEED; ++d) r[d] = lr[d];

        float w[32];
        w[31] = INFINITY;
#pragma unroll
        for (int d = 0; d < 31; ++d) w[d] = r[d];
        sort32(w);
#pragma unroll
        for (int s = 0; s < RW; ++s) {
            hl[fl * HSTRH + tb + s] = (h16)w[15];
            if (s < RW - 1) slide(w, r[s], r[s + 31]);
        }
    }
    __syncthreads();
    // ---- phase P: percussive medians (slide along f) + combine + store ----
    {
        const int lane = tid & 63;        // t within tile
        const int fb   = (tid >> 6) * RW; // f chunk base 0,8,16,24
        const int t    = t0x + lane;

        float r[FEED];
#pragma unroll
        for (int d = 0; d < FEED; ++d) r[d] = tile[(fb + d) * TSTR + 16 + lane];
        h16 hp[RW];
#pragma unroll
        for (int s = 0; s < RW; ++s) hp[s] = hl[(fb + s) * HSTRH + lane];

        float w[32];
        w[31] = INFINITY;
#pragma unroll
        for (int d = 0; d < 31; ++d) w[d] = r[d];
        sort32(w);
#pragma unroll
        for (int s = 0; s < RW; ++s) {
            const int f = f0 + fb + s;
            if (f < DIM_F) {
                const float perc = w[15];
                const float harm = (float)hp[s];
                const float sv   = r[s + 15];   // center element, free
                const float h2 = harm * harm;
                const float p2 = perc * perc;
                const float inv = __builtin_amdgcn_rcpf(h2 + p2);  // 0 -> INF; (sv*0)*INF=NaN matches ref 0/0
                const size_t oi = ((size_t)b * DIM_F + f) * DIM_T + t;
                outH[oi] = sv * h2 * inv;
                outP[oi] = sv * p2 * inv;
            }
            if (s < RW - 1) slide(w, r[s], r[s + 31]);
        }
    }
}

__global__ __launch_bounds__(256, 5) void hpss_fused(const float* __restrict__ S,
                                                     float* __restrict__ outH,
                                                     float* __restrict__ outP) {
    __shared__ float tile[TROWS * TSTR];  // 24056 B
    __shared__ h16 hl[FT * HSTRH];        //  4224 B

    const int tid = threadIdx.x;
    const int t0A = blockIdx.x * (2 * TT);      // tile A
    const int t0B = t0A + TT;                   // tile B
    const int f0  = blockIdx.y * FT;
    const int b   = blockIdx.z;
    const float* __restrict__ Sb = S + (size_t)b * DIM_F * DIM_T;

    // stage tile A directly
#pragma unroll
    for (int it = 0; it < 6; ++it)
        write_vec(tile, it * 256 + tid, load_vec(Sb, f0, t0A, it * 256 + tid));

    // issue tile B loads NOW; consumed a full compute-phase later (T14)
    float4 bv[6];
#pragma unroll
    for (int it = 0; it < 6; ++it) bv[it] = load_vec(Sb, f0, t0B, it * 256 + tid);

    __syncthreads();
    compute_tile(tile, hl, outH, outP, tid, f0, b, t0A);
    __syncthreads();                    // all waves done reading tile A

#pragma unroll
    for (int it = 0; it < 6; ++it) write_vec(tile, it * 256 + tid, bv[it]);
    __syncthreads();
    compute_tile(tile, hl, outH, outP, tid, f0, b, t0B);
}

extern "C" void kernel_launch(void* const* d_in, const int* in_sizes, int n_in,
                              void* d_out, int out_size, void* d_ws, size_t ws_size,
                              hipStream_t stream) {
    const float* S = (const float*)d_in[0];
    float* outH = (float*)d_out;
    float* outP = outH + (size_t)2 * DIM_F * DIM_T;

    dim3 grid(DIM_T / (2 * TT), (DIM_F + FT - 1) / FT, 2);  // 16 x 33 x 2 = 1056
    hpss_fused<<<grid, 256, 0, stream>>>(S, outH, outP);
}

// Round 21
// 31.970 us; speedup vs baseline: 1.5652x; 1.2931x over previous
//
#include <hip/hip_runtime.h>
#include <math.h>

// HPSS fused — PACKED fp16 dual-tile edition (r20 compile-fixed).
// S (2,1,1025,2048) fp32. harm = median_31 along T (zero pad), perc = along F.
// outH = S*h^2/(h^2+p^2), outP = S*p^2/(h^2+p^2)   (softmask Z cancels).
//
// Two adjacent 32(f)x64(t) tiles (A,B) staged INTERLEAVED as half2:
// tile[row][col] = pack(fp16(A), fp16(B)). Every ds_read_b32 feeds both
// tiles; sort/slide run on v_pk_min/max_f16 (1 CE = 2 ops for 2 windows).
// Slide delete is VCC-free bitwise select:
//   m = (short2)(w[i]-xo) >> 15; D[i] = (w[i]&m) | (w[i+1]&~m)   (v_bfi)
// insert: w'[i] = pk_min(pk_max(D[i-1], xn), D[i]) (D sorted => med3).
// Static floor 15.5 -> ~11us; LDS ops halved; 2 barriers/block (was 5).
// Numerics: fp16 container proven r7-r12 (absmax 0.0039 vs 2e-2 threshold);
// cvt_pkrtz (RTZ) monotone => median commutes; packed-sub sign exact.
// r20 fix: cvt_pkrtz returns __fp16x2 -> route through union (bit-identical).

#define DIM_T 2048
#define DIM_F 1025
#define HALF 15
#define FT 32            // output f-rows per tile
#define TT 64            // output t-cols per tile (x2 tiles per block)
#define RW 8             // outputs per thread along sliding axis
#define TROWS (FT + 30)  // 62 staged rows
#define VPR 24           // float4 vecs per row (96 cols, [t0-16, t0+80))
#define TSTR 97          // h16x2 elements (dwords); odd -> conflict-free
#define HSTR 65          // hl stride in dwords (odd)
#define NVEC (TROWS * VPR)   // 1488
#define FEED (RW + 30)   // 38

typedef _Float16 h16;
typedef _Float16 h16x2 __attribute__((ext_vector_type(2)));
typedef __fp16 fp16x2 __attribute__((ext_vector_type(2)));
typedef short short2v __attribute__((ext_vector_type(2)));

union pku { h16x2 h; fp16x2 f; unsigned int u; short2v s; };

__device__ __forceinline__ h16x2 pmin(h16x2 a, h16x2 b) {
#if __has_builtin(__builtin_elementwise_min)
    return __builtin_elementwise_min(a, b);
#else
    h16x2 r; r.x = a.x < b.x ? a.x : b.x; r.y = a.y < b.y ? a.y : b.y; return r;
#endif
}
__device__ __forceinline__ h16x2 pmax(h16x2 a, h16x2 b) {
#if __has_builtin(__builtin_elementwise_max)
    return __builtin_elementwise_max(a, b);
#else
    h16x2 r; r.x = a.x > b.x ? a.x : b.x; r.y = a.y > b.y ? a.y : b.y; return r;
#endif
}

__device__ __forceinline__ void ce(h16x2& a, h16x2& b) {
    const h16x2 mn = pmin(a, b);
    b = pmax(a, b);
    a = mn;
}

// Batcher-32, CEs touching index 31 pruned (w[31] = +INF pair is inert).
__device__ __forceinline__ void sort32(h16x2 (&a)[32]) {
#pragma unroll
    for (int p = 1; p < 32; p <<= 1) {
#pragma unroll
        for (int k = p; k >= 1; k >>= 1) {
#pragma unroll
            for (int j = k & (p - 1); j + k < 32; j += 2 * k) {
#pragma unroll
                for (int i = 0; i < k; ++i) {
                    if (i + j + k < 31) {
                        if ((i + j) / (2 * p) == (i + j + k) / (2 * p)) {
                            ce(a[i + j], a[i + j + k]);
                        }
                    }
                }
            }
        }
    }
}

// packed sorted-window slide: per half, remove xo (present in w[0..30]),
// insert xn. w[31] = +INF pair, preserved.
__device__ __forceinline__ void slide(h16x2 (&w)[32], h16x2 xo, h16x2 xn) {
    pku m0, a0, b0, D0;
    m0.h = w[0] - xo;                 // packed sub — sign exact
    m0.s = m0.s >> 15;                // ones where w<xo
    a0.h = w[0]; b0.h = w[1];
    D0.u = (a0.u & m0.u) | (b0.u & ~m0.u);   // v_bfi_b32
    h16x2 dprev = D0.h;
    h16x2 rprev = pmin(xn, dprev);
#pragma unroll
    for (int i = 1; i < 31; ++i) {
        pku mi, ai, bi, Di;
        mi.h = w[i] - xo;
        mi.s = mi.s >> 15;
        ai.h = w[i]; bi.h = w[i + 1];
        Di.u = (ai.u & mi.u) | (bi.u & ~mi.u);
        const h16x2 ri = pmin(pmax(dprev, xn), Di.h);  // med3 (D sorted)
        w[i - 1] = rprev;
        dprev = Di.h;
        rprev = ri;
    }
    w[30] = rprev;
}

// load one staging float4 for tile at t0x (vec index li)
__device__ __forceinline__ float4 load_vec(const float* __restrict__ Sb,
                                           int f0, int t0x, int li) {
    float4 v = make_float4(0.f, 0.f, 0.f, 0.f);
    if (li < NVEC) {
        const int row = li / VPR;
        const int pos = li - row * VPR;
        const int f  = f0 - HALF + row;
        const int tg = t0x - 16 + pos * 4;
        if ((unsigned)f < (unsigned)DIM_F && (unsigned)tg <= (unsigned)(DIM_T - 4))
            v = *(const float4*)&Sb[(size_t)f * DIM_T + tg];
    }
    return v;
}

__device__ __forceinline__ h16x2 pack2(float a, float b) {
    pku t;
    t.f = __builtin_amdgcn_cvt_pkrtz(a, b);  // RTZ, monotone
    return t.h;
}

// write interleaved pack(A,B) as 4 dwords
__device__ __forceinline__ void write_vec_pk(h16x2* __restrict__ tile, int li,
                                             float4 a, float4 b) {
    if (li < NVEC) {
        const int row = li / VPR;
        const int pos = li - row * VPR;
        h16x2* p = &tile[row * TSTR + pos * 4];
        p[0] = pack2(a.x, b.x);
        p[1] = pack2(a.y, b.y);
        p[2] = pack2(a.z, b.z);
        p[3] = pack2(a.w, b.w);
    }
}

__global__ __launch_bounds__(256, 4) void hpss_fused(const float* __restrict__ S,
                                                     float* __restrict__ outH,
                                                     float* __restrict__ outP) {
    __shared__ h16x2 tile[TROWS * TSTR];  // 24056 B (packed A|B)
    __shared__ h16x2 hl[FT * HSTR];       //  8320 B (packed harm A|B)

    const int tid = threadIdx.x;
    const int t0A = blockIdx.x * (2 * TT);      // tile A cols
    const int t0B = t0A + TT;                   // tile B cols
    const int f0  = blockIdx.y * FT;
    const int b   = blockIdx.z;
    const float* __restrict__ Sb = S + (size_t)b * DIM_F * DIM_T;

    // ---- stage both tiles interleaved as half2, coalesced ----
#pragma unroll
    for (int it = 0; it < 6; ++it) {
        const int li = it * 256 + tid;
        const float4 vA = load_vec(Sb, f0, t0A, li);
        const float4 vB = load_vec(Sb, f0, t0B, li);
        write_vec_pk(tile, li, vA, vB);
    }
    __syncthreads();

    pku inf; inf.u = 0x7C007C00u;   // +INF | +INF

    // ---- phase H: packed harmonic medians (slide along t) -> hl ----
    {
        const int fl = tid & 31;          // output f row 0..31
        const int tb = (tid >> 5) * RW;   // t chunk base 0..56
        const h16x2* lr = tile + (fl + HALF) * TSTR + tb + 1;

        h16x2 r[FEED];
#pragma unroll
        for (int d = 0; d < FEED; ++d) r[d] = lr[d];

        h16x2 w[32];
        w[31] = inf.h;
#pragma unroll
        for (int d = 0; d < 31; ++d) w[d] = r[d];
        sort32(w);
#pragma unroll
        for (int s = 0; s < RW; ++s) {
            hl[fl * HSTR + tb + s] = w[15];
            if (s < RW - 1) slide(w, r[s], r[s + 31]);
        }
    }
    __syncthreads();

    // ---- phase P: packed percussive medians + combine + store ----
    {
        const int lane = tid & 63;        // t within tile
        const int fb   = (tid >> 6) * RW; // f chunk base 0,8,16,24

        h16x2 r[FEED];
#pragma unroll
        for (int d = 0; d < FEED; ++d) r[d] = tile[(fb + d) * TSTR + 16 + lane];
        h16x2 hp[RW];
#pragma unroll
        for (int s = 0; s < RW; ++s) hp[s] = hl[(fb + s) * HSTR + lane];

        h16x2 w[32];
        w[31] = inf.h;
#pragma unroll
        for (int d = 0; d < 31; ++d) w[d] = r[d];
        sort32(w);
#pragma unroll
        for (int s = 0; s < RW; ++s) {
            const int f = f0 + fb + s;
            if (f < DIM_F) {
                const h16x2 pc = w[15], hm = hp[s], sv = r[s + 15];
                // tile A (lo half)
                {
                    const float harm = (float)hm.x, perc = (float)pc.x;
                    const float h2 = harm * harm, p2 = perc * perc;
                    const float inv = __builtin_amdgcn_rcpf(h2 + p2); // 0->INF; 0*INF=NaN matches ref
                    const size_t oi = ((size_t)b * DIM_F + f) * DIM_T + (t0A + lane);
                    outH[oi] = (float)sv.x * h2 * inv;
                    outP[oi] = (float)sv.x * p2 * inv;
                }
                // tile B (hi half)
                {
                    const float harm = (float)hm.y, perc = (float)pc.y;
                    const float h2 = harm * harm, p2 = perc * perc;
                    const float inv = __builtin_amdgcn_rcpf(h2 + p2);
                    const size_t oi = ((size_t)b * DIM_F + f) * DIM_T + (t0B + lane);
                    outH[oi] = (float)sv.y * h2 * inv;
                    outP[oi] = (float)sv.y * p2 * inv;
                }
            }
            if (s < RW - 1) slide(w, r[s], r[s + 31]);
        }
    }
}

extern "C" void kernel_launch(void* const* d_in, const int* in_sizes, int n_in,
                              void* d_out, int out_size, void* d_ws, size_t ws_size,
                              hipStream_t stream) {
    const float* S = (const float*)d_in[0];
    float* outH = (float*)d_out;
    float* outP = outH + (size_t)2 * DIM_F * DIM_T;

    dim3 grid(DIM_T / (2 * TT), (DIM_F + FT - 1) / FT, 2);  // 16 x 33 x 2 = 1056
    hpss_fused<<<grid, 256, 0, stream>>>(S, outH, outP);
}